// Round 26
// baseline (874.180 us; speedup 1.0000x reference)
//
#include <hip/hip_runtime.h>
#include <hip/hip_bf16.h>
#include <stdint.h>

using u16 = unsigned short;
using u32 = unsigned int;

typedef __attribute__((ext_vector_type(8))) short short8;
typedef __attribute__((ext_vector_type(4))) short short4v;
typedef __attribute__((ext_vector_type(4))) float f32x4;

#define MFMA16(a,b,c) __builtin_amdgcn_mfma_f32_16x16x32_bf16(a,b,c,0,0,0)
#define QSCL 0.022542110325192448f   // AMULT * log2(e), folded into Q at proj epilogue

// NOTE (journal): r25 native f2bf banked (859us). r26: router -> MFMA GEMM:
// rw split into bf16 hi+lo (logits error ~1e-4 << tolerated h2-bf16 error,
// top-8 selection unchanged), two accumulating k_gemm dispatches (MODE3/8,
// grid 1x32) + per-thread k_top8 (exact old selection logic). Replaces the
// 4096-block router that re-read 196KB rw per block (~800MB L2 traffic).

__device__ __forceinline__ u16 f2bf(float f){
  __hip_bfloat16 b = __float2bfloat16(f);
  return *reinterpret_cast<u16*>(&b);
}
__device__ __forceinline__ float bf2f(u16 b){ return __uint_as_float(((u32)b)<<16); }

__device__ __forceinline__ void gload16(const void* g, void* l){
  __builtin_amdgcn_global_load_lds(
      (const __attribute__((address_space(1))) u32*)g,
      (__attribute__((address_space(3))) u32*)l, 16, 0, 0);
}

// 16-lane sum reduction via compiler-known DPP (row_ror) — VALU-only, hazard-safe
template<int CTRL>
__device__ __forceinline__ float dppf(float x){
  return __int_as_float(__builtin_amdgcn_mov_dpp(__float_as_int(x), CTRL, 0xf, 0xf, true));
}
__device__ __forceinline__ float red16_sum(float x){
  x += dppf<0x128>(x);
  x += dppf<0x124>(x);
  x += dppf<0x122>(x);
  x += dppf<0x121>(x);
  return x;
}

//------------------------------------------------------------------
// Weight prep: src f32 [K][N] -> dst bf16 [N][K], 64x64 coalesced tiles
__global__ __launch_bounds__(256) void k_wt(const float* __restrict__ src,
    u16* __restrict__ dst, int K, int N, long sstride, long dstride)
{
  __shared__ float tile[64][65];
  int nb = blockIdx.x*64, kb = blockIdx.y*64;
  const float* S = src + (long)blockIdx.z*sstride;
  u16* D = dst + (long)blockIdx.z*dstride;
  int tid = threadIdx.x;
  int rr = tid>>4, c4 = (tid&15)*4;
  #pragma unroll
  for (int p=0;p<4;++p){
    int r = p*16 + rr;
    f32x4 v = *(const f32x4*)&S[(long)(kb+r)*N + nb + c4];
    tile[r][c4+0]=v[0]; tile[r][c4+1]=v[1]; tile[r][c4+2]=v[2]; tile[r][c4+3]=v[3];
  }
  __syncthreads();
  #pragma unroll
  for (int p=0;p<4;++p){
    int nn = p*16 + rr;
    short4v o;
    #pragma unroll
    for (int i=0;i<4;++i) o[i] = (short)f2bf(tile[c4+i][nn]);
    *(short4v*)&D[(long)(nb+nn)*K + kb + c4] = o;
  }
}

//------------------------------------------------------------------
// Interleaved weight prep (16-col subtile gate/up interleave), 64x64 tiles
__global__ __launch_bounds__(256) void k_wti(const float* __restrict__ src,
    u16* __restrict__ dst, int K, int N, int halfN, long sstride, long dstride)
{
  __shared__ float tile[64][65];
  int nb = blockIdx.x*64, kb = blockIdx.y*64;
  const float* S = src + (long)blockIdx.z*sstride;
  u16* D = dst + (long)blockIdx.z*dstride;
  int tid = threadIdx.x;
  int rr = tid>>4, c4 = (tid&15)*4;
  int scol = (nb>>1) + ((c4>>5)<<4) + (c4&15) + (((c4>>4)&1)? halfN : 0);
  #pragma unroll
  for (int p=0;p<4;++p){
    int r = p*16 + rr;
    f32x4 v = *(const f32x4*)&S[(long)(kb+r)*N + scol];
    tile[r][c4+0]=v[0]; tile[r][c4+1]=v[1]; tile[r][c4+2]=v[2]; tile[r][c4+3]=v[3];
  }
  __syncthreads();
  #pragma unroll
  for (int p=0;p<4;++p){
    int nn = p*16 + rr;
    short4v o;
    #pragma unroll
    for (int i=0;i<4;++i) o[i] = (short)f2bf(tile[c4+i][nn]);
    *(short4v*)&D[(long)(nb+nn)*K + kb + c4] = o;
  }
}

//------------------------------------------------------------------
// Router weight prep: rw f32 [1536][32] -> hi/lo bf16 [128][1536]
// (rows 0..31 filled; rows 32..127 pre-zeroed by memset)
__global__ __launch_bounds__(256) void k_rwt(const float* __restrict__ rw,
    u16* __restrict__ hi, u16* __restrict__ lo)
{
  int i = blockIdx.x*256 + threadIdx.x;   // 49152 = 32*1536
  int e = i / 1536, d = i - e*1536;
  float v = rw[(long)d*32 + e];
  u16 h = f2bf(v);
  float r = v - bf2f(h);
  hi[(long)e*1536 + d] = h;
  lo[(long)e*1536 + d] = f2bf(r);
}

//------------------------------------------------------------------
// V transpose: v (stride 2560, offset pre-applied) -> vT [8][64][4096]
__global__ __launch_bounds__(256) void k_vt(const u16* __restrict__ v,
                                            u16* __restrict__ vT)
{
  __shared__ u16 t_[64*72];
  int t0 = blockIdx.x*64, kvh = blockIdx.y;
  int tid = threadIdx.x;
  #pragma unroll
  for (int i=0;i<2;++i){
    int c = tid + i*256;
    int row = c>>3, dc = (c&7)*8;
    *(short8*)&t_[row*72 + dc] = *(const short8*)&v[(long)(t0+row)*2560 + kvh*64 + dc];
  }
  __syncthreads();
  #pragma unroll
  for (int i=0;i<2;++i){
    int c = tid + i*256;
    int d = c>>3, tc = (c&7)*8;
    short8 o;
    #pragma unroll
    for (int j=0;j<8;++j) o[j] = (short)t_[(tc+j)*72 + d];
    *(short8*)&vT[(long)(kvh*64 + d)*4096 + t0 + tc] = o;
  }
}

//------------------------------------------------------------------
// RMSNorm: f32 [T,1536] -> bf16 [T,1536]
__global__ __launch_bounds__(192) void k_rmsnorm(const float* __restrict__ x,
                                                 const float* __restrict__ w,
                                                 u16* __restrict__ o)
{
  int t = blockIdx.x, tid = threadIdx.x;
  const float* xr = x + (size_t)t*1536 + tid*8;
  f32x4 a = *(const f32x4*)xr;
  f32x4 b = *(const f32x4*)(xr+4);
  float ss = a[0]*a[0]+a[1]*a[1]+a[2]*a[2]+a[3]*a[3]
           + b[0]*b[0]+b[1]*b[1]+b[2]*b[2]+b[3]*b[3];
  #pragma unroll
  for (int m=1;m<64;m<<=1) ss += __shfl_xor(ss,m);
  __shared__ float red[3];
  if ((tid&63)==0) red[tid>>6]=ss;
  __syncthreads();
  float inv = rsqrtf((red[0]+red[1]+red[2])*(1.0f/1536.0f)+1e-6f);
  const float* wp = w + tid*8;
  f32x4 wa = *(const f32x4*)wp;
  f32x4 wb = *(const f32x4*)(wp+4);
  u16* op = o + (size_t)t*1536 + tid*8;
  #pragma unroll
  for (int j=0;j<4;++j) op[j]   = f2bf(a[j]*inv*wa[j]);
  #pragma unroll
  for (int j=0;j<4;++j) op[j+4] = f2bf(b[j]*inv*wb[j]);
}

//------------------------------------------------------------------
// m97-style 128x128 GEMM, BK=64, XOR-swizzled LDS. SWZN>0: XCD-aware
// bijective 1D block remap (expert GEMMs).
// MODE 0: Cb = bf16(acc)
// MODE 1: Cf[idx] = resid[idx] + acc*0.22
// MODE 3: Cf = acc          MODE 8: Cf += acc   (router logits hi/lo)
// MODE 5: Cb[roff+gr] = bf16(acc * gates[roff+gr])
// MODE 6: interleaved gate/up B; silu(acc[m][2k])*acc[m][2k+1]
// MODE 7: MODE0 + fused RoPE for col0<2048; q (col<1536) scaled by QSCL
template<int MODE, int GATHER, int SWZN=0>
__global__ __launch_bounds__(256, (MODE==5||MODE==6)?4:3) void k_gemm(
    const u16* __restrict__ A, int lda,
    const u16* __restrict__ Bt, long strideB, int K,
    int Mfix, const int* __restrict__ cnts, const int* __restrict__ offs,
    const int* __restrict__ toks, const float* __restrict__ gates,
    u16* __restrict__ Cb, int ldcb,
    float* __restrict__ Cf, int ldcf,
    const float* __restrict__ resid, const int* __restrict__ pos)
{
  int e, bx, by;
  if constexpr(SWZN > 0){
    int t = blockIdx.x;
    int elo = t & 7;
    int u = t >> 3;
    int per = SWZN*32;
    int chunk = u / per;
    int inner = u - chunk*per;
    e  = elo + 8*chunk;
    bx = inner % SWZN;
    by = inner / SWZN;
  } else {
    e = blockIdx.z; bx = blockIdx.x; by = blockIdx.y;
  }
  int M = cnts ? cnts[e] : Mfix;
  int m0 = by*128;
  if (m0 >= M) return;
  int roff = offs ? offs[e] : 0;
  const u16* Bp = Bt + (long)e*strideB;
  int col0 = bx*128;

  __shared__ u16 Ash[128*64];
  __shared__ u16 Bsh[128*64];

  int tid = threadIdx.x, wv = tid>>6, lane = tid&63;
  int lr = lane&15, lg = lane>>4;
  int wr = (wv>>1)*64, wc = (wv&1)*64;

  int rsub = lane>>3;
  int ksw = ((lane&7) ^ rsub)*8;
  const u16* apt[4];
  const u16* bpt[4];
  #pragma unroll
  for (int p=0;p<4;++p){
    int rloc = p*32 + wv*8 + rsub;
    int gr = min(m0 + rloc, M-1);
    int ar = GATHER ? toks[roff + gr] : (roff + gr);
    apt[p] = A + (long)ar*lda + ksw;
    bpt[p] = Bp + (long)(col0 + rloc)*K + ksw;
  }

  f32x4 acc[4][4];
  #pragma unroll
  for (int m=0;m<4;++m)
    #pragma unroll
    for (int n=0;n<4;++n)
      acc[m][n] = (f32x4){0.f,0.f,0.f,0.f};

  int nk = K>>6;
  for (int kt=0; kt<nk; ++kt){
    __syncthreads();
    #pragma unroll
    for (int p=0;p<4;++p){
      gload16(apt[p], &Ash[(p*32 + wv*8)*64]);
      gload16(bpt[p], &Bsh[(p*32 + wv*8)*64]);
      apt[p] += 64; bpt[p] += 64;
    }
    __syncthreads();

    #pragma unroll
    for (int kk=0;kk<2;++kk){
      short8 af[4], b1[4];
      #pragma unroll
      for (int m=0;m<4;++m)
        af[m] = *(const short8*)&Ash[(wr+m*16+lr)*64 + (((kk*4+lg)^(lr&7))*8)];
      #pragma unroll
      for (int n=0;n<4;++n)
        b1[n] = *(const short8*)&Bsh[(wc+n*16+lr)*64 + (((kk*4+lg)^(lr&7))*8)];
      #pragma unroll
      for (int m=0;m<4;++m)
        #pragma unroll
        for (int n=0;n<4;++n)
          acc[m][n] = MFMA16(af[m], b1[n], acc[m][n]);
    }
  }

  if constexpr(MODE==6){
    #pragma unroll
    for (int m=0;m<4;++m)
      #pragma unroll
      for (int np=0;np<2;++np)
        #pragma unroll
        for (int rr=0;rr<4;++rr){
          int row = wr + m*16 + lg*4 + rr;
          int gr = m0 + row;
          if (gr >= M) continue;
          float g = acc[m][2*np][rr];
          float u = acc[m][2*np+1][rr];
          float s = g/(1.f+__expf(-g))*u;
          int j = (wc>>1) + np*16 + lr;
          Cb[(long)(roff+gr)*ldcb + (col0>>1) + j] = f2bf(s);
        }
  } else if constexpr(MODE==7){
    if (col0 < 2048){
      float invf0 = __expf(-(float)lr      * 0.28782313662425574f);
      float invf1 = __expf(-(float)(lr+16) * 0.28782313662425574f);
      float qs = (col0 < 1536) ? QSCL : 1.0f;
      #pragma unroll
      for (int m=0;m<4;++m)
        #pragma unroll
        for (int rr=0;rr<4;++rr){
          int gr = m0 + wr + m*16 + lg*4 + rr;
          float pv = (float)pos[gr];
          #pragma unroll
          for (int n=0;n<2;++n){
            float sn, cs;
            __sincosf(pv * (n ? invf1 : invf0), &sn, &cs);
            float x1 = acc[m][n][rr], x2 = acc[m][n+2][rr];
            long base = (long)gr*ldcb + col0 + wc + n*16 + lr;
            Cb[base]      = f2bf((x1*cs - x2*sn)*qs);
            Cb[base + 32] = f2bf((x2*cs + x1*sn)*qs);
          }
        }
    } else {
      #pragma unroll
      for (int m=0;m<4;++m)
        #pragma unroll
        for (int n=0;n<4;++n)
          #pragma unroll
          for (int rr=0;rr<4;++rr){
            int gr = m0 + wr + m*16 + lg*4 + rr;
            int col = wc + n*16 + lr;
            Cb[(long)gr*ldcb + col0 + col] = f2bf(acc[m][n][rr]);
          }
    }
  } else {
    #pragma unroll
    for (int m=0;m<4;++m)
      #pragma unroll
      for (int n=0;n<4;++n)
        #pragma unroll
        for (int rr=0;rr<4;++rr){
          int row = wr + m*16 + lg*4 + rr;
          int gr = m0 + row;
          if (gr >= M) continue;
          int col = wc + n*16 + lr;
          float va = acc[m][n][rr];
          if constexpr(MODE==0){
            Cb[(long)(roff+gr)*ldcb + col0 + col] = f2bf(va);
          } else if constexpr(MODE==1){
            long idx = (long)gr*ldcf + col0 + col;
            Cf[idx] = resid[idx] + va*0.22f;
          } else if constexpr(MODE==3){
            Cf[(long)gr*ldcf + col0 + col] = va;
          } else if constexpr(MODE==8){
            Cf[(long)gr*ldcf + col0 + col] += va;
          } else if constexpr(MODE==5){
            float gt = gates[roff+gr];
            Cb[(long)(roff+gr)*ldcb + col0 + col] = f2bf(va*gt);
          }
        }
  }
}

//------------------------------------------------------------------
// Top-8 + gate softmax from precomputed logits [4096][128] (cols 0..31 valid)
__global__ __launch_bounds__(256) void k_top8(const float* __restrict__ logits,
    int* __restrict__ topi, float* __restrict__ gatev)
{
  int t = blockIdx.x*256 + threadIdx.x;   // 4096 threads
  float lgt[32];
  #pragma unroll
  for (int j=0;j<32;++j) lgt[j] = logits[(long)t*128 + j];
  u32 msk=0; float tv[8]; int ti[8];
  #pragma unroll
  for (int kk=0;kk<8;++kk){
    float best=-1e30f; int bi=0;
    #pragma unroll
    for (int j2=0;j2<32;++j2)
      if (!((msk>>j2)&1u) && lgt[j2] > best){ best=lgt[j2]; bi=j2; }
    msk |= 1u<<bi; tv[kk]=best; ti[kk]=bi;
  }
  float mx = tv[0], ssum = 0.f, ge[8];
  #pragma unroll
  for (int kk=0;kk<8;++kk){ ge[kk]=__expf(tv[kk]-mx); ssum+=ge[kk]; }
  float isum = 1.f/ssum;
  #pragma unroll
  for (int kk=0;kk<8;++kk){ topi[t*8+kk]=ti[kk]; gatev[t*8+kk]=ge[kk]*isum; }
}

//------------------------------------------------------------------
// MoE sum: out[t] += sum_{kk} part[inv[t*8+kk]]  (partials pre-scaled)
__global__ __launch_bounds__(192) void k_moesum(const u16* __restrict__ part,
    const int* __restrict__ inv, float* __restrict__ out)
{
  int t = blockIdx.x, tid = threadIdx.x;
  int c = tid*8;
  float s[8] = {0.f,0.f,0.f,0.f,0.f,0.f,0.f,0.f};
  #pragma unroll
  for (int kk=0;kk<8;++kk){
    int slot = inv[t*8+kk];
    short8 v = *(const short8*)&part[(long)slot*1536 + c];
    #pragma unroll
    for (int j=0;j<8;++j) s[j] += bf2f((u16)v[j]);
  }
  float* op = out + (long)t*1536 + c;
  f32x4 o0 = *(const f32x4*)op;
  f32x4 o1 = *(const f32x4*)(op+4);
  #pragma unroll
  for (int j=0;j<4;++j){ o0[j] += s[j]; o1[j] += s[j+4]; }
  *(f32x4*)op = o0;
  *(f32x4*)(op+4) = o1;
}

//------------------------------------------------------------------
// Causal flash attention with KV-split (r22 structure). Fixed-m softmax
// (m=0): P = exp2(S) directly, l = sum P. Psh stride 68 (2-way writes).
__global__ __launch_bounds__(256,3) void k_attn(const u16* __restrict__ qg,
    const u16* __restrict__ kg, const u16* __restrict__ vT,
    u16* __restrict__ og, u16* __restrict__ Opart, float* __restrict__ mlb)
{
  int bid = blockIdx.x;               // 768 = 96 x 8
  int kvh = bid & 7;
  int ii = bid >> 3;
  int qt, kt0, kt1, chunk; bool single;
  if (ii < 32)      { qt = 32+ii;        chunk = 0; kt0 = 0;  kt1 = 32;   single = false; }
  else if (ii < 64) { qt = ii;           chunk = 1; kt0 = 32; kt1 = qt+1; single = false; }
  else              { qt = 31-(ii-64);   chunk = 0; kt0 = 0;  kt1 = qt+1; single = true;  }

  int tid = threadIdx.x, wv = tid>>6, lane = tid&63;
  int lr = lane&15, lg = lane>>4;
  __shared__ u16 Ksh[64*72];
  __shared__ u16 Vsh[64*72];
  __shared__ u16 Psh[4][16*68];   // stride 68: b16 writes 2-way (free)
  int q0 = qt*64;
  int qrow = q0 + wv*16 + lr;
  short8 qf[3][2];
  #pragma unroll
  for (int hh=0;hh<3;++hh)
    #pragma unroll
    for (int c=0;c<2;++c)
      qf[hh][c] = *(const short8*)&qg[(long)qrow*2560 + (kvh*3+hh)*64 + c*32 + lg*8];

  float l_[3][4];
  f32x4 Ot[3][4];
  #pragma unroll
  for (int hh=0;hh<3;++hh)
    #pragma unroll
    for (int r=0;r<4;++r) l_[hh][r]=0.f;
  #pragma unroll
  for (int hh=0;hh<3;++hh)
    #pragma unroll
    for (int d=0;d<4;++d) Ot[hh][d]=(f32x4){0.f,0.f,0.f,0.f};

  int srow = tid>>3, sdc = (tid&7)*8;
  short8 kreg[2], vreg[2];
  auto loadKV = [&](int kt){
    #pragma unroll
    for (int i=0;i<2;++i){
      int row = srow + i*32;
      kreg[i] = *(const short8*)&kg[(long)(kt*64+row)*2560 + kvh*64 + sdc];
      vreg[i] = *(const short8*)&vT[(long)(kvh*64 + row)*4096 + kt*64 + sdc];
    }
  };
  loadKV(kt0);

  for (int kt=kt0; kt<kt1; ++kt){
    __syncthreads();
    #pragma unroll
    for (int i=0;i<2;++i){
      int row = srow + i*32;
      *(short8*)&Ksh[row*72 + sdc] = kreg[i];
      *(short8*)&Vsh[row*72 + sdc] = vreg[i];
    }
    __syncthreads();
    if (kt < kt1-1) loadKV(kt+1);
    bool diag = (kt==qt);

    #pragma unroll
    for (int hh=0;hh<3;++hh){
      f32x4 S[4];
      #pragma unroll
      for (int n=0;n<4;++n) S[n]=(f32x4){0.f,0.f,0.f,0.f};
      #pragma unroll
      for (int n=0;n<4;++n)
        #pragma unroll
        for (int c=0;c<2;++c){
          short8 kf = *(const short8*)&Ksh[(n*16+lr)*72 + c*32 + lg*8];
          S[n] = MFMA16(qf[hh][c], kf, S[n]);
        }

      // fixed-m softmax: P = exp2(S) directly (S bounded, log2 units)
      float rsum[4] = {0.f,0.f,0.f,0.f};
      #pragma unroll
      for (int n=0;n<4;++n)
        #pragma unroll
        for (int r=0;r<4;++r){
          float sv = S[n][r];
          if (diag){
            int colg = n*16 + lr;
            int rowg = wv*16 + lg*4 + r;
            if (colg > rowg) sv = -1e30f;
          }
          float pv = exp2f(sv);
          S[n][r] = pv;
          rsum[r] += pv;
        }
      #pragma unroll
      for (int r=0;r<4;++r) rsum[r] = red16_sum(rsum[r]);
      #pragma unroll
      for (int r=0;r<4;++r) l_[hh][r] += rsum[r];

      #pragma unroll
      for (int n=0;n<4;++n)
        #pragma unroll
        for (int r=0;r<4;++r)
          Psh[wv][(lg*4+r)*68 + n*16 + lr] = f2bf(S[n][r]);
      #pragma unroll
      for (int c=0;c<2;++c){
        short8 pf = *(const short8*)&Psh[wv][lr*68 + c*32 + lg*8];
        #pragma unroll
        for (int d=0;d<4;++d){
          short8 vf = *(const short8*)&Vsh[(d*16+lr)*72 + c*32 + lg*8];
          Ot[hh][d] = MFMA16(pf, vf, Ot[hh][d]);
        }
      }
    }
  }

  if (single){
    #pragma unroll
    for (int hh=0;hh<3;++hh)
      #pragma unroll
      for (int d=0;d<4;++d)
        #pragma unroll
        for (int r=0;r<4;++r){
          int t = q0 + wv*16 + lg*4 + r;
          og[(long)t*1536 + (kvh*3+hh)*64 + d*16 + lr] = f2bf(Ot[hh][d][r]/l_[hh][r]);
        }
  } else {
    #pragma unroll
    for (int hh=0;hh<3;++hh){
      int h = kvh*3+hh;
      #pragma unroll
      for (int r=0;r<4;++r){
        int t = q0 + wv*16 + lg*4 + r;
        long slot = ((long)(t-2048)*24 + h)*2 + chunk;
        #pragma unroll
        for (int d=0;d<4;++d)
          Opart[slot*64 + d*16 + lr] = f2bf(Ot[hh][d][r]);
        if (lr==0) mlb[slot] = l_[hh][r];
      }
    }
  }
}

//------------------------------------------------------------------
// Combine the two KV-split partials for t>=2048: O=(O0+O1)/(l0+l1)
__global__ __launch_bounds__(256) void k_comb(const u16* __restrict__ Opart,
    const float* __restrict__ mlb, u16* __restrict__ og)
{
  int gid = blockIdx.x*256 + threadIdx.x;   // 2048*24*64
  int d = gid & 63;
  long rowi = gid >> 6;                      // t'*24 + h
  long s0 = rowi*2, s1 = s0+1;
  float l0 = mlb[s0], l1 = mlb[s1];
  float o = (bf2f(Opart[s0*64+d]) + bf2f(Opart[s1*64+d])) / (l0 + l1);
  int t = 2048 + (int)(rowi/24), h = (int)(rowi - (rowi/24)*24);
  og[(long)t*1536 + h*64 + d] = f2bf(o);
}

__global__ void k_hist(const int* __restrict__ topi, int* __restrict__ cnt){
  int i = blockIdx.x*256 + threadIdx.x;
  if (i < 4096*8) atomicAdd(&cnt[topi[i]], 1);
}
__global__ void k_scan(const int* __restrict__ cnt, int* __restrict__ offs, int* __restrict__ cur){
  if (threadIdx.x==0 && blockIdx.x==0){
    int a=0;
    for (int e2=0;e2<32;++e2){ offs[e2]=a; cur[e2]=a; a+=cnt[e2]; }
  }
}
__global__ void k_scatter(const int* __restrict__ topi, const float* __restrict__ gatev,
    int* __restrict__ cur, int* __restrict__ toks, float* __restrict__ gts,
    int* __restrict__ inv){
  int i = blockIdx.x*256 + threadIdx.x;
  if (i < 4096*8){
    int e2 = topi[i];
    int p = atomicAdd(&cur[e2], 1);
    toks[p] = i>>3;
    gts[p] = gatev[i]*0.22f;
    inv[i] = p;
  }
}

//------------------------------------------------------------------
extern "C" void kernel_launch(void* const* d_in, const int* in_sizes, int n_in,
                              void* d_out, int out_size, void* d_ws, size_t ws_size,
                              hipStream_t stream)
{
  const int*   positions = (const int*)  d_in[0];
  const float* hs   = (const float*)d_in[1];
  const float* ln1w = (const float*)d_in[2];
  const float* wq   = (const float*)d_in[3];
  const float* wk   = (const float*)d_in[4];
  const float* wv   = (const float*)d_in[5];
  const float* wo   = (const float*)d_in[6];
  const float* ln2w = (const float*)d_in[7];
  const float* rww  = (const float*)d_in[8];
  const float* wgu  = (const float*)d_in[9];
  const float* wdn  = (const float*)d_in[10];
  const float* sgu  = (const float*)d_in[11];
  const float* sdn  = (const float*)d_in[12];
  float* out = (float*)d_out;

  char* ws = (char*)d_ws;
  size_t off = 0;
  auto alloc = [&](size_t b)->void*{ void* p = ws + off; off += (b + 255) & ~(size_t)255; return p; };

  u16* hbf     = (u16*)alloc((size_t)4096*1536*2);   // ln1 out; attn Opart; later h2
  u16* qkv     = (u16*)alloc((size_t)33554432);
  u16* qkvb = qkv;                                   // [4096][2560] packed q|k|v
  u16* aout = qkv + (size_t)4096*2560;               // [4096][1536]
  u16* act_moe = qkv;                                // overlays after o-proj
  u16* act_sh  = (u16*)alloc((size_t)4096*1024*2);   // also attn l buffer
  u16* vT      = (u16*)alloc((size_t)8*64*4096*2);
  float* logits= (float*)alloc((size_t)4096*128*4);  // router logits (cols 0..31)
  int*   topi  = (int*)  alloc(4096*8*4);
  float* gatev = (float*)alloc(4096*8*4);
  int*   toks  = (int*)  alloc(4096*8*4);
  float* gts   = (float*)alloc(4096*8*4);
  int*   inv   = (int*)  alloc(4096*8*4);
  int*   cnt   = (int*)  alloc(512);
  int*   offs  = (int*)  alloc(512);
  int*   cur   = (int*)  alloc(512);
  u16* wqkvT = (u16*)alloc((size_t)2560*1536*2);     // rows: wq | wk | wv
  u16* woT  = (u16*)alloc((size_t)1536*1536*2);
  u16* sguT = (u16*)alloc((size_t)2048*1536*2);
  u16* sdnT = (u16*)alloc((size_t)1536*1024*2);
  u16* rwhi = (u16*)alloc((size_t)128*1536*2);       // router weights hi (padded)
  u16* rwlo = (u16*)alloc((size_t)128*1536*2);       // router weights lo (padded)
  u16* wguT = (u16*)alloc((size_t)32*1024*1536*2);
  u16* wdnT = (u16*)alloc((size_t)32*1536*512*2);
  float* hidden2 = out;
  u16*   h2bf = hbf;
  u16*   Opart = hbf;            // dead between qkv-proj and ln2
  float* mlb   = (float*)act_sh; // dead until shared gate_up
  u16*   part  = wguT;           // dead after moe gate_up consumes it

  // 0. weight convert+transpose (bf16 [N][K]); 64x64 coalesced tiles
  k_wt <<<dim3(24,24,1), 256,0,stream>>>(wq,  wqkvT,                   1536,1536, 0,0);
  k_wt <<<dim3(8,24,1),  256,0,stream>>>(wk,  wqkvT+(size_t)1536*1536, 1536,512,  0,0);
  k_wt <<<dim3(8,24,1),  256,0,stream>>>(wv,  wqkvT+(size_t)2048*1536, 1536,512,  0,0);
  k_wt <<<dim3(24,24,1), 256,0,stream>>>(wo,  woT,  1536,1536, 0,0);
  k_wti<<<dim3(32,24,1), 256,0,stream>>>(sgu, sguT, 1536,2048,1024, 0,0);
  k_wt <<<dim3(24,16,1), 256,0,stream>>>(sdn, sdnT, 1024,1536, 0,0);
  k_wti<<<dim3(16,24,32),256,0,stream>>>(wgu, wguT, 1536,1024,512, (long)1536*1024, (long)1536*1024);
  k_wt <<<dim3(24,8,32), 256,0,stream>>>(wdn, wdnT, 512,1536,  (long)512*1536,  (long)512*1536);
  hipMemsetAsync(rwhi, 0, (size_t)128*1536*2, stream);
  hipMemsetAsync(rwlo, 0, (size_t)128*1536*2, stream);
  k_rwt<<<192,256,0,stream>>>(rww, rwhi, rwlo);

  // 1. ln1
  k_rmsnorm<<<4096,192,0,stream>>>(hs, ln1w, hbf);
  // 2. fused q|k|v projection + RoPE (+Q exp2-prescale) -> qkvb [4096][2560]
  k_gemm<7,0><<<dim3(20,32,1),256,0,stream>>>(hbf,1536, wqkvT,0,1536, 4096,nullptr,nullptr,nullptr,nullptr, qkvb,2560, nullptr,0, nullptr, positions);
  // 3. V transpose
  k_vt<<<dim3(64,8,1),256,0,stream>>>(qkvb + 2048, vT);
  // 4. flash attention with KV-split (balanced block order), then combine
  k_attn<<<dim3(768,1,1),256,0,stream>>>(qkvb, qkvb + 1536, vT, aout, Opart, mlb);
  k_comb<<<12288,256,0,stream>>>(Opart, mlb, aout);
  // 5. o-proj + residual -> hidden2 (in d_out)
  k_gemm<1,0><<<dim3(12,32,1),256,0,stream>>>(aout,1536, woT,0,1536, 4096,nullptr,nullptr,nullptr,nullptr, nullptr,0, hidden2,1536, hs, nullptr);
  // 6. ln2
  k_rmsnorm<<<4096,192,0,stream>>>(hidden2, ln2w, h2bf);
  // 7. router logits via MFMA (hi + lo accumulate), then top-8, then grouping
  k_gemm<3,0><<<dim3(1,32,1),256,0,stream>>>(h2bf,1536, rwhi,0,1536, 4096,nullptr,nullptr,nullptr,nullptr, nullptr,0, logits,128, nullptr, nullptr);
  k_gemm<8,0><<<dim3(1,32,1),256,0,stream>>>(h2bf,1536, rwlo,0,1536, 4096,nullptr,nullptr,nullptr,nullptr, nullptr,0, logits,128, nullptr, nullptr);
  k_top8<<<16,256,0,stream>>>(logits, topi, gatev);
  hipMemsetAsync(cnt, 0, 32*4, stream);
  k_hist<<<128,256,0,stream>>>(topi, cnt);
  k_scan<<<1,64,0,stream>>>(cnt, offs, cur);
  k_scatter<<<128,256,0,stream>>>(topi, gatev, cur, toks, gts, inv);
  // 8. moe gate_up + silu*mul (gathered rows, interleaved B; XCD-swizzled)
  k_gemm<6,1,8><<<dim3(8192,1,1),256,0,stream>>>(h2bf,1536, wguT,(long)1024*1536,1536, 0,cnt,offs,toks,nullptr, act_moe,512, nullptr,0, nullptr, nullptr);
  // 9. shared gate_up + silu*mul (interleaved B)
  k_gemm<6,0><<<dim3(16,32,1),256,0,stream>>>(h2bf,1536, sguT,0,1536, 4096,nullptr,nullptr,nullptr,nullptr, act_sh,1024, nullptr,0, nullptr, nullptr);
  // 10. shared down: out = hidden2 + shared*0.22
  k_gemm<1,0><<<dim3(12,32,1),256,0,stream>>>(act_sh,1024, sdnT,0,1024, 4096,nullptr,nullptr,nullptr,nullptr, nullptr,0, out,1536, out, nullptr);
  // 11. moe down -> gate-scaled bf16 partials (XCD-swizzled, overlays dead wguT)
  k_gemm<5,0,12><<<dim3(12288,1,1),256,0,stream>>>(act_moe,512, wdnT,(long)1536*512,512, 0,cnt,offs,nullptr,gts, part,1536, nullptr,0, nullptr, nullptr);
  // 12. sum the 8 partials per token onto out
  k_moesum<<<4096,192,0,stream>>>(part, inv, out);

  (void)in_sizes; (void)n_in; (void)out_size; (void)ws_size;
}

// Round 27
// 851.863 us; speedup vs baseline: 1.0262x; 1.0262x over previous
//
#include <hip/hip_runtime.h>
#include <hip/hip_bf16.h>
#include <stdint.h>

using u16 = unsigned short;
using u32 = unsigned int;

typedef __attribute__((ext_vector_type(8))) short short8;
typedef __attribute__((ext_vector_type(4))) short short4v;
typedef __attribute__((ext_vector_type(4))) float f32x4;

#define MFMA16(a,b,c) __builtin_amdgcn_mfma_f32_16x16x32_bf16(a,b,c,0,0,0)
#define QSCL 0.022542110325192448f   // AMULT * log2(e), folded into Q at proj epilogue

// NOTE (journal): r26 router-GEMM REGRESSED (+15us: 32-block dispatches
// starve the GPU; latency-bound) — router reverted to r25 k_router. r27:
// attn softmax denominator via MFMA: l = P·ones using the SAME pf fragment
// as PV (one extra MFMA per c-chunk, B=bf16 ones). Removes rsum+red16_sum
// (~150 VALU ops/tile of the ~700 VALU-bound budget). l now accumulated in
// Lt[3] f32x4 across tiles (bf16-P-consistent denominator, shift ~5e-4).

__device__ __forceinline__ u16 f2bf(float f){
  __hip_bfloat16 b = __float2bfloat16(f);
  return *reinterpret_cast<u16*>(&b);
}
__device__ __forceinline__ float bf2f(u16 b){ return __uint_as_float(((u32)b)<<16); }

__device__ __forceinline__ void gload16(const void* g, void* l){
  __builtin_amdgcn_global_load_lds(
      (const __attribute__((address_space(1))) u32*)g,
      (__attribute__((address_space(3))) u32*)l, 16, 0, 0);
}

//------------------------------------------------------------------
// Weight prep: src f32 [K][N] -> dst bf16 [N][K], 64x64 coalesced tiles
__global__ __launch_bounds__(256) void k_wt(const float* __restrict__ src,
    u16* __restrict__ dst, int K, int N, long sstride, long dstride)
{
  __shared__ float tile[64][65];
  int nb = blockIdx.x*64, kb = blockIdx.y*64;
  const float* S = src + (long)blockIdx.z*sstride;
  u16* D = dst + (long)blockIdx.z*dstride;
  int tid = threadIdx.x;
  int rr = tid>>4, c4 = (tid&15)*4;
  #pragma unroll
  for (int p=0;p<4;++p){
    int r = p*16 + rr;
    f32x4 v = *(const f32x4*)&S[(long)(kb+r)*N + nb + c4];
    tile[r][c4+0]=v[0]; tile[r][c4+1]=v[1]; tile[r][c4+2]=v[2]; tile[r][c4+3]=v[3];
  }
  __syncthreads();
  #pragma unroll
  for (int p=0;p<4;++p){
    int nn = p*16 + rr;
    short4v o;
    #pragma unroll
    for (int i=0;i<4;++i) o[i] = (short)f2bf(tile[c4+i][nn]);
    *(short4v*)&D[(long)(nb+nn)*K + kb + c4] = o;
  }
}

//------------------------------------------------------------------
// Interleaved weight prep (16-col subtile gate/up interleave), 64x64 tiles
__global__ __launch_bounds__(256) void k_wti(const float* __restrict__ src,
    u16* __restrict__ dst, int K, int N, int halfN, long sstride, long dstride)
{
  __shared__ float tile[64][65];
  int nb = blockIdx.x*64, kb = blockIdx.y*64;
  const float* S = src + (long)blockIdx.z*sstride;
  u16* D = dst + (long)blockIdx.z*dstride;
  int tid = threadIdx.x;
  int rr = tid>>4, c4 = (tid&15)*4;
  int scol = (nb>>1) + ((c4>>5)<<4) + (c4&15) + (((c4>>4)&1)? halfN : 0);
  #pragma unroll
  for (int p=0;p<4;++p){
    int r = p*16 + rr;
    f32x4 v = *(const f32x4*)&S[(long)(kb+r)*N + scol];
    tile[r][c4+0]=v[0]; tile[r][c4+1]=v[1]; tile[r][c4+2]=v[2]; tile[r][c4+3]=v[3];
  }
  __syncthreads();
  #pragma unroll
  for (int p=0;p<4;++p){
    int nn = p*16 + rr;
    short4v o;
    #pragma unroll
    for (int i=0;i<4;++i) o[i] = (short)f2bf(tile[c4+i][nn]);
    *(short4v*)&D[(long)(nb+nn)*K + kb + c4] = o;
  }
}

//------------------------------------------------------------------
// V transpose: v (stride 2560, offset pre-applied) -> vT [8][64][4096]
__global__ __launch_bounds__(256) void k_vt(const u16* __restrict__ v,
                                            u16* __restrict__ vT)
{
  __shared__ u16 t_[64*72];
  int t0 = blockIdx.x*64, kvh = blockIdx.y;
  int tid = threadIdx.x;
  #pragma unroll
  for (int i=0;i<2;++i){
    int c = tid + i*256;
    int row = c>>3, dc = (c&7)*8;
    *(short8*)&t_[row*72 + dc] = *(const short8*)&v[(long)(t0+row)*2560 + kvh*64 + dc];
  }
  __syncthreads();
  #pragma unroll
  for (int i=0;i<2;++i){
    int c = tid + i*256;
    int d = c>>3, tc = (c&7)*8;
    short8 o;
    #pragma unroll
    for (int j=0;j<8;++j) o[j] = (short)t_[(tc+j)*72 + d];
    *(short8*)&vT[(long)(kvh*64 + d)*4096 + t0 + tc] = o;
  }
}

//------------------------------------------------------------------
// RMSNorm: f32 [T,1536] -> bf16 [T,1536]
__global__ __launch_bounds__(192) void k_rmsnorm(const float* __restrict__ x,
                                                 const float* __restrict__ w,
                                                 u16* __restrict__ o)
{
  int t = blockIdx.x, tid = threadIdx.x;
  const float* xr = x + (size_t)t*1536 + tid*8;
  f32x4 a = *(const f32x4*)xr;
  f32x4 b = *(const f32x4*)(xr+4);
  float ss = a[0]*a[0]+a[1]*a[1]+a[2]*a[2]+a[3]*a[3]
           + b[0]*b[0]+b[1]*b[1]+b[2]*b[2]+b[3]*b[3];
  #pragma unroll
  for (int m=1;m<64;m<<=1) ss += __shfl_xor(ss,m);
  __shared__ float red[3];
  if ((tid&63)==0) red[tid>>6]=ss;
  __syncthreads();
  float inv = rsqrtf((red[0]+red[1]+red[2])*(1.0f/1536.0f)+1e-6f);
  const float* wp = w + tid*8;
  f32x4 wa = *(const f32x4*)wp;
  f32x4 wb = *(const f32x4*)(wp+4);
  u16* op = o + (size_t)t*1536 + tid*8;
  #pragma unroll
  for (int j=0;j<4;++j) op[j]   = f2bf(a[j]*inv*wa[j]);
  #pragma unroll
  for (int j=0;j<4;++j) op[j+4] = f2bf(b[j]*inv*wb[j]);
}

//------------------------------------------------------------------
// m97-style 128x128 GEMM, BK=64, XOR-swizzled LDS. SWZN>0: XCD-aware
// bijective 1D block remap (expert GEMMs).
// MODE 0: Cb = bf16(acc)
// MODE 1: Cf[idx] = resid[idx] + acc*0.22
// MODE 5: Cb[roff+gr] = bf16(acc * gates[roff+gr])
// MODE 6: interleaved gate/up B; silu(acc[m][2k])*acc[m][2k+1]
// MODE 7: MODE0 + fused RoPE for col0<2048; q (col<1536) scaled by QSCL
template<int MODE, int GATHER, int SWZN=0>
__global__ __launch_bounds__(256, (MODE==5||MODE==6)?4:3) void k_gemm(
    const u16* __restrict__ A, int lda,
    const u16* __restrict__ Bt, long strideB, int K,
    int Mfix, const int* __restrict__ cnts, const int* __restrict__ offs,
    const int* __restrict__ toks, const float* __restrict__ gates,
    u16* __restrict__ Cb, int ldcb,
    float* __restrict__ Cf, int ldcf,
    const float* __restrict__ resid, const int* __restrict__ pos)
{
  int e, bx, by;
  if constexpr(SWZN > 0){
    int t = blockIdx.x;
    int elo = t & 7;
    int u = t >> 3;
    int per = SWZN*32;
    int chunk = u / per;
    int inner = u - chunk*per;
    e  = elo + 8*chunk;
    bx = inner % SWZN;
    by = inner / SWZN;
  } else {
    e = blockIdx.z; bx = blockIdx.x; by = blockIdx.y;
  }
  int M = cnts ? cnts[e] : Mfix;
  int m0 = by*128;
  if (m0 >= M) return;
  int roff = offs ? offs[e] : 0;
  const u16* Bp = Bt + (long)e*strideB;
  int col0 = bx*128;

  __shared__ u16 Ash[128*64];
  __shared__ u16 Bsh[128*64];

  int tid = threadIdx.x, wv = tid>>6, lane = tid&63;
  int lr = lane&15, lg = lane>>4;
  int wr = (wv>>1)*64, wc = (wv&1)*64;

  int rsub = lane>>3;
  int ksw = ((lane&7) ^ rsub)*8;
  const u16* apt[4];
  const u16* bpt[4];
  #pragma unroll
  for (int p=0;p<4;++p){
    int rloc = p*32 + wv*8 + rsub;
    int gr = min(m0 + rloc, M-1);
    int ar = GATHER ? toks[roff + gr] : (roff + gr);
    apt[p] = A + (long)ar*lda + ksw;
    bpt[p] = Bp + (long)(col0 + rloc)*K + ksw;
  }

  f32x4 acc[4][4];
  #pragma unroll
  for (int m=0;m<4;++m)
    #pragma unroll
    for (int n=0;n<4;++n)
      acc[m][n] = (f32x4){0.f,0.f,0.f,0.f};

  int nk = K>>6;
  for (int kt=0; kt<nk; ++kt){
    __syncthreads();
    #pragma unroll
    for (int p=0;p<4;++p){
      gload16(apt[p], &Ash[(p*32 + wv*8)*64]);
      gload16(bpt[p], &Bsh[(p*32 + wv*8)*64]);
      apt[p] += 64; bpt[p] += 64;
    }
    __syncthreads();

    #pragma unroll
    for (int kk=0;kk<2;++kk){
      short8 af[4], b1[4];
      #pragma unroll
      for (int m=0;m<4;++m)
        af[m] = *(const short8*)&Ash[(wr+m*16+lr)*64 + (((kk*4+lg)^(lr&7))*8)];
      #pragma unroll
      for (int n=0;n<4;++n)
        b1[n] = *(const short8*)&Bsh[(wc+n*16+lr)*64 + (((kk*4+lg)^(lr&7))*8)];
      #pragma unroll
      for (int m=0;m<4;++m)
        #pragma unroll
        for (int n=0;n<4;++n)
          acc[m][n] = MFMA16(af[m], b1[n], acc[m][n]);
    }
  }

  if constexpr(MODE==6){
    #pragma unroll
    for (int m=0;m<4;++m)
      #pragma unroll
      for (int np=0;np<2;++np)
        #pragma unroll
        for (int rr=0;rr<4;++rr){
          int row = wr + m*16 + lg*4 + rr;
          int gr = m0 + row;
          if (gr >= M) continue;
          float g = acc[m][2*np][rr];
          float u = acc[m][2*np+1][rr];
          float s = g/(1.f+__expf(-g))*u;
          int j = (wc>>1) + np*16 + lr;
          Cb[(long)(roff+gr)*ldcb + (col0>>1) + j] = f2bf(s);
        }
  } else if constexpr(MODE==7){
    if (col0 < 2048){
      float invf0 = __expf(-(float)lr      * 0.28782313662425574f);
      float invf1 = __expf(-(float)(lr+16) * 0.28782313662425574f);
      float qs = (col0 < 1536) ? QSCL : 1.0f;
      #pragma unroll
      for (int m=0;m<4;++m)
        #pragma unroll
        for (int rr=0;rr<4;++rr){
          int gr = m0 + wr + m*16 + lg*4 + rr;
          float pv = (float)pos[gr];
          #pragma unroll
          for (int n=0;n<2;++n){
            float sn, cs;
            __sincosf(pv * (n ? invf1 : invf0), &sn, &cs);
            float x1 = acc[m][n][rr], x2 = acc[m][n+2][rr];
            long base = (long)gr*ldcb + col0 + wc + n*16 + lr;
            Cb[base]      = f2bf((x1*cs - x2*sn)*qs);
            Cb[base + 32] = f2bf((x2*cs + x1*sn)*qs);
          }
        }
    } else {
      #pragma unroll
      for (int m=0;m<4;++m)
        #pragma unroll
        for (int n=0;n<4;++n)
          #pragma unroll
          for (int rr=0;rr<4;++rr){
            int gr = m0 + wr + m*16 + lg*4 + rr;
            int col = wc + n*16 + lr;
            Cb[(long)gr*ldcb + col0 + col] = f2bf(acc[m][n][rr]);
          }
    }
  } else {
    #pragma unroll
    for (int m=0;m<4;++m)
      #pragma unroll
      for (int n=0;n<4;++n)
        #pragma unroll
        for (int rr=0;rr<4;++rr){
          int row = wr + m*16 + lg*4 + rr;
          int gr = m0 + row;
          if (gr >= M) continue;
          int col = wc + n*16 + lr;
          float va = acc[m][n][rr];
          if constexpr(MODE==0){
            Cb[(long)(roff+gr)*ldcb + col0 + col] = f2bf(va);
          } else if constexpr(MODE==1){
            long idx = (long)gr*ldcf + col0 + col;
            Cf[idx] = resid[idx] + va*0.22f;
          } else if constexpr(MODE==5){
            float gt = gates[roff+gr];
            Cb[(long)(roff+gr)*ldcb + col0 + col] = f2bf(va*gt);
          }
        }
  }
}

//------------------------------------------------------------------
// MoE sum: out[t] += sum_{kk} part[inv[t*8+kk]]  (partials pre-scaled)
__global__ __launch_bounds__(192) void k_moesum(const u16* __restrict__ part,
    const int* __restrict__ inv, float* __restrict__ out)
{
  int t = blockIdx.x, tid = threadIdx.x;
  int c = tid*8;
  float s[8] = {0.f,0.f,0.f,0.f,0.f,0.f,0.f,0.f};
  #pragma unroll
  for (int kk=0;kk<8;++kk){
    int slot = inv[t*8+kk];
    short8 v = *(const short8*)&part[(long)slot*1536 + c];
    #pragma unroll
    for (int j=0;j<8;++j) s[j] += bf2f((u16)v[j]);
  }
  float* op = out + (long)t*1536 + c;
  f32x4 o0 = *(const f32x4*)op;
  f32x4 o1 = *(const f32x4*)(op+4);
  #pragma unroll
  for (int j=0;j<4;++j){ o0[j] += s[j]; o1[j] += s[j+4]; }
  *(f32x4*)op = o0;
  *(f32x4*)(op+4) = o1;
}

//------------------------------------------------------------------
// Causal flash attention with KV-split (r22 structure). Fixed-m softmax
// (m=0): P = exp2(S) directly. Denominator l = P·ones via MFMA (reuses the
// PV pf fragment; B = bf16 ones) — no VALU row-reduce. Psh stride 68.
__global__ __launch_bounds__(256,3) void k_attn(const u16* __restrict__ qg,
    const u16* __restrict__ kg, const u16* __restrict__ vT,
    u16* __restrict__ og, u16* __restrict__ Opart, float* __restrict__ mlb)
{
  int bid = blockIdx.x;               // 768 = 96 x 8
  int kvh = bid & 7;
  int ii = bid >> 3;
  int qt, kt0, kt1, chunk; bool single;
  if (ii < 32)      { qt = 32+ii;        chunk = 0; kt0 = 0;  kt1 = 32;   single = false; }
  else if (ii < 64) { qt = ii;           chunk = 1; kt0 = 32; kt1 = qt+1; single = false; }
  else              { qt = 31-(ii-64);   chunk = 0; kt0 = 0;  kt1 = qt+1; single = true;  }

  int tid = threadIdx.x, wv = tid>>6, lane = tid&63;
  int lr = lane&15, lg = lane>>4;
  __shared__ u16 Ksh[64*72];
  __shared__ u16 Vsh[64*72];
  __shared__ u16 Psh[4][16*68];   // stride 68: b16 writes 2-way (free)
  int q0 = qt*64;
  int qrow = q0 + wv*16 + lr;
  short8 qf[3][2];
  #pragma unroll
  for (int hh=0;hh<3;++hh)
    #pragma unroll
    for (int c=0;c<2;++c)
      qf[hh][c] = *(const short8*)&qg[(long)qrow*2560 + (kvh*3+hh)*64 + c*32 + lg*8];

  const short8 onesf = {(short)0x3F80,(short)0x3F80,(short)0x3F80,(short)0x3F80,
                        (short)0x3F80,(short)0x3F80,(short)0x3F80,(short)0x3F80};
  f32x4 Lt[3];
  f32x4 Ot[3][4];
  #pragma unroll
  for (int hh=0;hh<3;++hh){
    Lt[hh]=(f32x4){0.f,0.f,0.f,0.f};
    #pragma unroll
    for (int d=0;d<4;++d) Ot[hh][d]=(f32x4){0.f,0.f,0.f,0.f};
  }

  int srow = tid>>3, sdc = (tid&7)*8;
  short8 kreg[2], vreg[2];
  auto loadKV = [&](int kt){
    #pragma unroll
    for (int i=0;i<2;++i){
      int row = srow + i*32;
      kreg[i] = *(const short8*)&kg[(long)(kt*64+row)*2560 + kvh*64 + sdc];
      vreg[i] = *(const short8*)&vT[(long)(kvh*64 + row)*4096 + kt*64 + sdc];
    }
  };
  loadKV(kt0);

  for (int kt=kt0; kt<kt1; ++kt){
    __syncthreads();
    #pragma unroll
    for (int i=0;i<2;++i){
      int row = srow + i*32;
      *(short8*)&Ksh[row*72 + sdc] = kreg[i];
      *(short8*)&Vsh[row*72 + sdc] = vreg[i];
    }
    __syncthreads();
    if (kt < kt1-1) loadKV(kt+1);
    bool diag = (kt==qt);

    #pragma unroll
    for (int hh=0;hh<3;++hh){
      f32x4 S[4];
      #pragma unroll
      for (int n=0;n<4;++n) S[n]=(f32x4){0.f,0.f,0.f,0.f};
      #pragma unroll
      for (int n=0;n<4;++n)
        #pragma unroll
        for (int c=0;c<2;++c){
          short8 kf = *(const short8*)&Ksh[(n*16+lr)*72 + c*32 + lg*8];
          S[n] = MFMA16(qf[hh][c], kf, S[n]);
        }

      // fixed-m softmax: P = exp2(S) directly (S bounded, log2 units)
      #pragma unroll
      for (int n=0;n<4;++n)
        #pragma unroll
        for (int r=0;r<4;++r){
          float sv = S[n][r];
          if (diag){
            int colg = n*16 + lr;
            int rowg = wv*16 + lg*4 + r;
            if (colg > rowg) sv = -1e30f;
          }
          S[n][r] = exp2f(sv);
        }

      #pragma unroll
      for (int n=0;n<4;++n)
        #pragma unroll
        for (int r=0;r<4;++r)
          Psh[wv][(lg*4+r)*68 + n*16 + lr] = f2bf(S[n][r]);
      #pragma unroll
      for (int c=0;c<2;++c){
        short8 pf = *(const short8*)&Psh[wv][lr*68 + c*32 + lg*8];
        Lt[hh] = MFMA16(pf, onesf, Lt[hh]);   // l += row-sum(P) on matrix pipe
        #pragma unroll
        for (int d=0;d<4;++d){
          short8 vf = *(const short8*)&Vsh[(d*16+lr)*72 + c*32 + lg*8];
          Ot[hh][d] = MFMA16(pf, vf, Ot[hh][d]);
        }
      }
    }
  }

  if (single){
    #pragma unroll
    for (int hh=0;hh<3;++hh)
      #pragma unroll
      for (int d=0;d<4;++d)
        #pragma unroll
        for (int r=0;r<4;++r){
          int t = q0 + wv*16 + lg*4 + r;
          og[(long)t*1536 + (kvh*3+hh)*64 + d*16 + lr] = f2bf(Ot[hh][d][r]/Lt[hh][r]);
        }
  } else {
    #pragma unroll
    for (int hh=0;hh<3;++hh){
      int h = kvh*3+hh;
      #pragma unroll
      for (int r=0;r<4;++r){
        int t = q0 + wv*16 + lg*4 + r;
        long slot = ((long)(t-2048)*24 + h)*2 + chunk;
        #pragma unroll
        for (int d=0;d<4;++d)
          Opart[slot*64 + d*16 + lr] = f2bf(Ot[hh][d][r]);
        if (lr==0) mlb[slot] = Lt[hh][r];
      }
    }
  }
}

//------------------------------------------------------------------
// Combine the two KV-split partials for t>=2048: O=(O0+O1)/(l0+l1)
__global__ __launch_bounds__(256) void k_comb(const u16* __restrict__ Opart,
    const float* __restrict__ mlb, u16* __restrict__ og)
{
  int gid = blockIdx.x*256 + threadIdx.x;   // 2048*24*64
  int d = gid & 63;
  long rowi = gid >> 6;                      // t'*24 + h
  long s0 = rowi*2, s1 = s0+1;
  float l0 = mlb[s0], l1 = mlb[s1];
  float o = (bf2f(Opart[s0*64+d]) + bf2f(Opart[s1*64+d])) / (l0 + l1);
  int t = 2048 + (int)(rowi/24), h = (int)(rowi - (rowi/24)*24);
  og[(long)t*1536 + h*64 + d] = f2bf(o);
}

//------------------------------------------------------------------
// Router: 256 threads/block, 8 segments x 32 experts, LDS reduce, f32 math
__global__ __launch_bounds__(256) void k_router(const u16* __restrict__ h2,
    const float* __restrict__ rw, int* __restrict__ topi, float* __restrict__ gatev)
{
  int t = blockIdx.x, tid = threadIdx.x;
  int e = tid & 31, seg = tid >> 5;
  const u16* hr = h2 + (size_t)t*1536 + seg*192;
  const float* wp = rw + (long)seg*192*32 + e;
  float s = 0.f;
  #pragma unroll 4
  for (int d=0; d<192; ++d)
    s += bf2f(hr[d]) * wp[(long)d*32];
  __shared__ float red[8][32];
  red[seg][e] = s;
  __syncthreads();
  __shared__ float lgt[32];
  if (tid < 32){
    float a = 0.f;
    #pragma unroll
    for (int g=0; g<8; ++g) a += red[g][tid];
    lgt[tid] = a;
  }
  __syncthreads();
  if (tid==0){
    u32 msk=0; float tv[8]; int ti[8];
    for (int kk=0;kk<8;++kk){
      float best=-1e30f; int bi=0;
      for (int j2=0;j2<32;++j2)
        if (!((msk>>j2)&1u) && lgt[j2] > best){ best=lgt[j2]; bi=j2; }
      msk |= 1u<<bi; tv[kk]=best; ti[kk]=bi;
    }
    float mx = tv[0], ssum = 0.f, ge[8];
    for (int kk=0;kk<8;++kk){ ge[kk]=__expf(tv[kk]-mx); ssum+=ge[kk]; }
    float isum = 1.f/ssum;
    for (int kk=0;kk<8;++kk){ topi[t*8+kk]=ti[kk]; gatev[t*8+kk]=ge[kk]*isum; }
  }
}

__global__ void k_hist(const int* __restrict__ topi, int* __restrict__ cnt){
  int i = blockIdx.x*256 + threadIdx.x;
  if (i < 4096*8) atomicAdd(&cnt[topi[i]], 1);
}
__global__ void k_scan(const int* __restrict__ cnt, int* __restrict__ offs, int* __restrict__ cur){
  if (threadIdx.x==0 && blockIdx.x==0){
    int a=0;
    for (int e2=0;e2<32;++e2){ offs[e2]=a; cur[e2]=a; a+=cnt[e2]; }
  }
}
__global__ void k_scatter(const int* __restrict__ topi, const float* __restrict__ gatev,
    int* __restrict__ cur, int* __restrict__ toks, float* __restrict__ gts,
    int* __restrict__ inv){
  int i = blockIdx.x*256 + threadIdx.x;
  if (i < 4096*8){
    int e2 = topi[i];
    int p = atomicAdd(&cur[e2], 1);
    toks[p] = i>>3;
    gts[p] = gatev[i]*0.22f;
    inv[i] = p;
  }
}

//------------------------------------------------------------------
extern "C" void kernel_launch(void* const* d_in, const int* in_sizes, int n_in,
                              void* d_out, int out_size, void* d_ws, size_t ws_size,
                              hipStream_t stream)
{
  const int*   positions = (const int*)  d_in[0];
  const float* hs   = (const float*)d_in[1];
  const float* ln1w = (const float*)d_in[2];
  const float* wq   = (const float*)d_in[3];
  const float* wk   = (const float*)d_in[4];
  const float* wv   = (const float*)d_in[5];
  const float* wo   = (const float*)d_in[6];
  const float* ln2w = (const float*)d_in[7];
  const float* rww  = (const float*)d_in[8];
  const float* wgu  = (const float*)d_in[9];
  const float* wdn  = (const float*)d_in[10];
  const float* sgu  = (const float*)d_in[11];
  const float* sdn  = (const float*)d_in[12];
  float* out = (float*)d_out;

  char* ws = (char*)d_ws;
  size_t off = 0;
  auto alloc = [&](size_t b)->void*{ void* p = ws + off; off += (b + 255) & ~(size_t)255; return p; };

  u16* hbf     = (u16*)alloc((size_t)4096*1536*2);   // ln1 out; attn Opart; later h2
  u16* qkv     = (u16*)alloc((size_t)33554432);
  u16* qkvb = qkv;                                   // [4096][2560] packed q|k|v
  u16* aout = qkv + (size_t)4096*2560;               // [4096][1536]
  u16* act_moe = qkv;                                // overlays after o-proj
  u16* act_sh  = (u16*)alloc((size_t)4096*1024*2);   // also attn l buffer
  u16* vT      = (u16*)alloc((size_t)8*64*4096*2);
  int*   topi  = (int*)  alloc(4096*8*4);
  float* gatev = (float*)alloc(4096*8*4);
  int*   toks  = (int*)  alloc(4096*8*4);
  float* gts   = (float*)alloc(4096*8*4);
  int*   inv   = (int*)  alloc(4096*8*4);
  int*   cnt   = (int*)  alloc(512);
  int*   offs  = (int*)  alloc(512);
  int*   cur   = (int*)  alloc(512);
  u16* wqkvT = (u16*)alloc((size_t)2560*1536*2);     // rows: wq | wk | wv
  u16* woT  = (u16*)alloc((size_t)1536*1536*2);
  u16* sguT = (u16*)alloc((size_t)2048*1536*2);
  u16* sdnT = (u16*)alloc((size_t)1536*1024*2);
  u16* wguT = (u16*)alloc((size_t)32*1024*1536*2);
  u16* wdnT = (u16*)alloc((size_t)32*1536*512*2);
  float* hidden2 = out;
  u16*   h2bf = hbf;
  u16*   Opart = hbf;            // dead between qkv-proj and ln2
  float* mlb   = (float*)act_sh; // dead until shared gate_up
  u16*   part  = wguT;           // dead after moe gate_up consumes it

  // 0. weight convert+transpose (bf16 [N][K]); 64x64 coalesced tiles
  k_wt <<<dim3(24,24,1), 256,0,stream>>>(wq,  wqkvT,                   1536,1536, 0,0);
  k_wt <<<dim3(8,24,1),  256,0,stream>>>(wk,  wqkvT+(size_t)1536*1536, 1536,512,  0,0);
  k_wt <<<dim3(8,24,1),  256,0,stream>>>(wv,  wqkvT+(size_t)2048*1536, 1536,512,  0,0);
  k_wt <<<dim3(24,24,1), 256,0,stream>>>(wo,  woT,  1536,1536, 0,0);
  k_wti<<<dim3(32,24,1), 256,0,stream>>>(sgu, sguT, 1536,2048,1024, 0,0);
  k_wt <<<dim3(24,16,1), 256,0,stream>>>(sdn, sdnT, 1024,1536, 0,0);
  k_wti<<<dim3(16,24,32),256,0,stream>>>(wgu, wguT, 1536,1024,512, (long)1536*1024, (long)1536*1024);
  k_wt <<<dim3(24,8,32), 256,0,stream>>>(wdn, wdnT, 512,1536,  (long)512*1536,  (long)512*1536);

  // 1. ln1
  k_rmsnorm<<<4096,192,0,stream>>>(hs, ln1w, hbf);
  // 2. fused q|k|v projection + RoPE (+Q exp2-prescale) -> qkvb [4096][2560]
  k_gemm<7,0><<<dim3(20,32,1),256,0,stream>>>(hbf,1536, wqkvT,0,1536, 4096,nullptr,nullptr,nullptr,nullptr, qkvb,2560, nullptr,0, nullptr, positions);
  // 3. V transpose
  k_vt<<<dim3(64,8,1),256,0,stream>>>(qkvb + 2048, vT);
  // 4. flash attention with KV-split (balanced block order), then combine
  k_attn<<<dim3(768,1,1),256,0,stream>>>(qkvb, qkvb + 1536, vT, aout, Opart, mlb);
  k_comb<<<12288,256,0,stream>>>(Opart, mlb, aout);
  // 5. o-proj + residual -> hidden2 (in d_out)
  k_gemm<1,0><<<dim3(12,32,1),256,0,stream>>>(aout,1536, woT,0,1536, 4096,nullptr,nullptr,nullptr,nullptr, nullptr,0, hidden2,1536, hs, nullptr);
  // 6. ln2
  k_rmsnorm<<<4096,192,0,stream>>>(hidden2, ln2w, h2bf);
  // 7. router + top-8 (256-thread, segment-split), then grouping
  k_router<<<4096,256,0,stream>>>(h2bf, rww, topi, gatev);
  hipMemsetAsync(cnt, 0, 32*4, stream);
  k_hist<<<128,256,0,stream>>>(topi, cnt);
  k_scan<<<1,64,0,stream>>>(cnt, offs, cur);
  k_scatter<<<128,256,0,stream>>>(topi, gatev, cur, toks, gts, inv);
  // 8. moe gate_up + silu*mul (gathered rows, interleaved B; XCD-swizzled)
  k_gemm<6,1,8><<<dim3(8192,1,1),256,0,stream>>>(h2bf,1536, wguT,(long)1024*1536,1536, 0,cnt,offs,toks,nullptr, act_moe,512, nullptr,0, nullptr, nullptr);
  // 9. shared gate_up + silu*mul (interleaved B)
  k_gemm<6,0><<<dim3(16,32,1),256,0,stream>>>(h2bf,1536, sguT,0,1536, 4096,nullptr,nullptr,nullptr,nullptr, act_sh,1024, nullptr,0, nullptr, nullptr);
  // 10. shared down: out = hidden2 + shared*0.22
  k_gemm<1,0><<<dim3(12,32,1),256,0,stream>>>(act_sh,1024, sdnT,0,1024, 4096,nullptr,nullptr,nullptr,nullptr, nullptr,0, out,1536, out, nullptr);
  // 11. moe down -> gate-scaled bf16 partials (XCD-swizzled, overlays dead wguT)
  k_gemm<5,0,12><<<dim3(12288,1,1),256,0,stream>>>(act_moe,512, wdnT,(long)1536*512,512, 0,cnt,offs,nullptr,gts, part,1536, nullptr,0, nullptr, nullptr);
  // 12. sum the 8 partials per token onto out
  k_moesum<<<4096,192,0,stream>>>(part, inv, out);

  (void)in_sizes; (void)n_in; (void)out_size; (void)ws_size;
}